// Round 17
// baseline (37008.258 us; speedup 1.0000x reference)
//
#include <hip/hip_runtime.h>
#include <hip/hip_bf16.h>

#define T_STEPS 8192
#define OBS 256
#define HID 2048
#define NOUT 256

#define NBLK 64    // scan blocks (1/CU on 64 CUs)
#define NTHR 1024  // 16 waves; wave owns 2 units (identical per-wave code to r14)

typedef unsigned long long u64;
typedef _Float16 half2v __attribute__((ext_vector_type(2)));
typedef __fp16 fp16x2 __attribute__((ext_vector_type(2)));

// ws layout:
//   [4096, 20480)  : h slots, 2 buffers x 1024 u64 {tag:u32 (hi), fp16x2 (lo)}
//                    slot j = hidden units 2j, 2j+1
//   [65536, +32MB) : hidden, T x HID bf16
#define WS_HBUF_OFF 4096
#define WS_HIDDEN_OFF 65536

__global__ void gru_init_kernel(u64* slots) {
  slots[blockIdx.x * 256 + threadIdx.x] = 0ull;  // 2048 u64
}

__device__ __forceinline__ half2v bc_h2(unsigned u) {
  union { unsigned u; half2v h; } c;
  c.u = u;
  return c.h;
}
__device__ __forceinline__ unsigned pk_rn(float lo, float hi) {
  union { half2v h; unsigned u; } c;
  c.h[0] = (_Float16)lo;  // RNE
  c.h[1] = (_Float16)hi;
  return c.u;
}
__device__ __forceinline__ unsigned pk_rtz(float lo, float hi) {
  union { fp16x2 h; unsigned u; } c;
  c.h = __builtin_amdgcn_cvt_pkrtz(lo, hi);
  return c.u;
}
__device__ __forceinline__ float fdot2f(unsigned a, unsigned b, float c) {
#if __has_builtin(__builtin_amdgcn_fdot2)
  return __builtin_amdgcn_fdot2(bc_h2(a), bc_h2(b), c, false);
#else
  const half2v ha = bc_h2(a), hb = bc_h2(b);
  return c + (float)ha[0] * (float)hb[0] + (float)ha[1] * (float)hb[1];
#endif
}

// r17 = r14 structure at HALF the participant count: 64 blocks x 1024 threads.
// Rationale: r8->r9 (256->128 participants) cut the step 3.9->2.63us; the
// publish->detect cost scales with the number of bursts the MALL serializes
// and the max-of-N detect tail. Per-wave code (and VGPR demand, 112) is
// byte-identical to r14 — 1024-thr blocks cap VGPRs at 128 (16 waves =
// 4/SIMD), so 112 fits; FETCH is the spill tripwire.
// Block w owns units w*32..+31; wave v owns units w*32+2v, +2v+1 (weight
// rows {i,H+i,2H+i} packed fp16, asm-pinned). Exchange: 1024 single-u64
// tagged pair-slots; thread tid polls slot tid; block publishes its 16 pairs
// as ONE 128B coalesced burst (threads 0..15, two whole lines, no cross-block
// line sharing — r13/r15 proved scattered publishes cost +1.1us/step).
// wi·x computed in-register during the poll wait (r14's win).
__global__ __launch_bounds__(NTHR, 4) void gru_scan_kernel(
    const float* __restrict__ ys, const float* __restrict__ wi,
    const float* __restrict__ wh, const float* __restrict__ b,
    const float* __restrict__ bn, __hip_bfloat16* __restrict__ hidden,
    u64* slots) {
  const int w = blockIdx.x;
  const int tid = threadIdx.x;
  const int wave = tid >> 6;
  const int lane = tid & 63;

  __shared__ __align__(16) unsigned hq_lds[2][HID / 2];  // fp16x2 pairs, 2x4KB
  __shared__ unsigned pair_lds[2][16];                   // per-wave fp16x2

  // ---- one-time: stage 6 rows/wave of wh,wi as packed fp16 in VGPRs ----
  unsigned whp[6][16];
  unsigned wip[6][4];
#pragma unroll
  for (int r = 0; r < 6; ++r) {
    const int g = r >> 1, e = r & 1;
    const size_t R = (size_t)(g * HID + w * 32 + 2 * wave + e);
#pragma unroll
    for (int m = 0; m < 8; ++m) {
      const float4 q =
          *reinterpret_cast<const float4*>(wh + R * HID + m * 256 + lane * 4);
      whp[r][2 * m] = pk_rn(q.x, q.y);
      whp[r][2 * m + 1] = pk_rn(q.z, q.w);
    }
#pragma unroll
    for (int p = 0; p < 2; ++p) {
      const float4 q =
          *reinterpret_cast<const float4*>(wi + R * 512 + p * 256 + lane * 4);
      wip[r][2 * p] = pk_rn(q.x, q.y);
      wip[r][2 * p + 1] = pk_rn(q.z, q.w);
    }
  }
#pragma unroll
  for (int r = 0; r < 6; ++r) {
#pragma unroll
    for (int m = 0; m < 16; ++m) asm volatile("" : "+v"(whp[r][m]));
#pragma unroll
    for (int p = 0; p < 4; ++p) asm volatile("" : "+v"(wip[r][p]));
  }

  // Gate constants for this wave's unit (lane&1 selects which of the pair).
  const int iu = w * 32 + 2 * wave + (lane & 1);
  const float b_r = b[iu];
  const float b_z = b[HID + iu];
  const float b_n = b[2 * HID + iu];
  const float bn_v = bn[iu];

  float h_own = 0.f;  // lanes 0,1: f32 recurrence state of own unit

#pragma unroll 1
  for (int s = 0; s < T_STEPS; ++s) {
    const int buf = s & 1;
    const u64* hp = slots + buf * 1024;
    u64* hp_next = slots + (buf ^ 1) * 1024;
    const unsigned tag = (unsigned)s;

    // ---- issue own-slot poll load FIRST (longest latency) ----
    u64 v = __hip_atomic_load(hp + tid, __ATOMIC_RELAXED,
                              __HIP_MEMORY_SCOPE_AGENT);

    // ---- h-independent work, overlapped with the poll wait ----
    const float4 yv =
        *reinterpret_cast<const float4*>(ys + (size_t)s * OBS + lane * 4);
    const bool k0 = (yv.x == yv.x), k1 = (yv.y == yv.y), k2 = (yv.z == yv.z),
               k3 = (yv.w == yv.w);
    unsigned xq[4];
    xq[0] = pk_rtz(k0 ? yv.x : 0.f, k1 ? yv.y : 0.f);
    xq[1] = pk_rtz(k2 ? yv.z : 0.f, k3 ? yv.w : 0.f);
    xq[2] = pk_rtz(k0 ? 1.f : 0.f, k1 ? 1.f : 0.f);
    xq[3] = pk_rtz(k2 ? 1.f : 0.f, k3 ? 1.f : 0.f);

    float pR[2], pZ[2], pIN[2];
#pragma unroll
    for (int e = 0; e < 2; ++e) {
      float ar = 0.f, az = 0.f, ain = 0.f;
#pragma unroll
      for (int p = 0; p < 4; ++p) {
        ar = fdot2f(wip[e][p], xq[p], ar);
        az = fdot2f(wip[2 + e][p], xq[p], az);
        ain = fdot2f(wip[4 + e][p], xq[p], ain);
      }
      pR[e] = ar;
      pZ[e] = az;
      pIN[e] = ain;
    }

    // ---- finish poll (single u64 slot: tag+payload atomic together) ----
    while ((unsigned)(v >> 32) != tag) {
      __builtin_amdgcn_s_sleep(1);
      v = __hip_atomic_load(hp + tid, __ATOMIC_RELAXED,
                            __HIP_MEMORY_SCOPE_AGENT);
    }

    // ---- stage pair tid ----
    hq_lds[buf][tid] = (unsigned)v;
    __syncthreads();  // sync1: all 1024 slots fresh + staged

    // ---- h fragments straight from LDS ----
    unsigned hq[16];
#pragma unroll
    for (int m = 0; m < 8; ++m) {
      const uint2 q =
          *reinterpret_cast<const uint2*>(&hq_lds[buf][m * 128 + lane * 2]);
      hq[2 * m] = q.x;
      hq[2 * m + 1] = q.y;
    }

    // ---- 8 dot accumulators, seeded with the wi·x partials ----
    float a[8];
#pragma unroll
    for (int e = 0; e < 2; ++e) {
      float ar = pR[e], az = pZ[e], ahn = 0.f;
      const int r0 = e, r1 = 2 + e, r2 = 4 + e;
#pragma unroll
      for (int m = 0; m < 16; ++m) {
        ar = fdot2f(whp[r0][m], hq[m], ar);
        az = fdot2f(whp[r1][m], hq[m], az);
        ahn = fdot2f(whp[r2][m], hq[m], ahn);
      }
      a[4 * e] = ar;
      a[4 * e + 1] = az;
      a[4 * e + 2] = ahn;
      a[4 * e + 3] = pIN[e];
    }

    // ---- combining butterfly: all 8 sums in 10 shuffles ----
#pragma unroll
    for (int j = 0; j < 4; ++j) {
      const bool sel = (lane & 1) != 0;
      const float keep = sel ? a[j + 4] : a[j];
      const float send = sel ? a[j] : a[j + 4];
      a[j] = keep + __shfl_xor(send, 1, 64);
    }
#pragma unroll
    for (int j = 0; j < 2; ++j) {
      const bool sel = (lane & 2) != 0;
      const float keep = sel ? a[j + 2] : a[j];
      const float send = sel ? a[j] : a[j + 2];
      a[j] = keep + __shfl_xor(send, 2, 64);
    }
    {
      const bool sel = (lane & 4) != 0;
      const float keep = sel ? a[1] : a[0];
      const float send = sel ? a[0] : a[1];
      a[0] = keep + __shfl_xor(send, 4, 64);
    }
    float redv = a[0];
    redv += __shfl_xor(redv, 8, 64);
    redv += __shfl_xor(redv, 16, 64);
    redv += __shfl_xor(redv, 32, 64);

    // Component c at lane rev3(c): r_e@lane e, z_e@4+e, hn_e@2+e, in_e@6+e.
    const int e = lane & 1;
    const float d_r = __shfl(redv, e, 64);
    const float d_z = __shfl(redv, 4 + e, 64);
    const float d_hn = __shfl(redv, 2 + e, 64);
    const float d_in = __shfl(redv, 6 + e, 64);

    // ---- gate math on all lanes (only lanes 0,1 hold valid state) ----
    const float rg = 1.f / (1.f + expf(-(d_r + b_r)));
    const float zg = 1.f / (1.f + expf(-(d_z + b_z)));
    const float ng = tanhf(d_in + b_n + rg * (d_hn + bn_v));
    const float hnew = ng + zg * (h_own - ng);
    h_own = hnew;  // garbage on lanes>=2, never consumed

    const float h1 = __shfl(hnew, 1, 64);
    if (lane == 0) {
      pair_lds[buf][wave] = pk_rtz(hnew, h1);
      // bf16 pair for the output head (off the critical path)
      const unsigned bf =
          ((unsigned)__bfloat16_as_ushort(__float2bfloat16(h1)) << 16) |
          (unsigned)__bfloat16_as_ushort(__float2bfloat16(hnew));
      *reinterpret_cast<unsigned*>(
          &hidden[(size_t)s * HID + w * 32 + 2 * wave]) = bf;
    }
    __syncthreads();  // sync2: all 16 wave-pairs in pair_lds

    // ---- aggregated publish: ONE 128B burst (16 lanes x u64, 2 lines) ----
    if (tid < 16) {
      const u64 pv = ((u64)(tag + 1) << 32) | (u64)pair_lds[buf][tid];
      __hip_atomic_store(hp_next + w * 16 + tid, pv, __ATOMIC_RELAXED,
                         __HIP_MEMORY_SCOPE_AGENT);
    }
    // No end-of-step barrier: LDS double-buffered by parity; same-parity
    // reuse is separated by two block-wide sync1s.
  }
}

// out[t][o] = bl[o] + sum_k hidden[t][k] * Wl[o][k]
// 64x64 tile, 256 threads, 4x4 micro-tile, BK=16.
__global__ __launch_bounds__(256) void out_gemm_kernel(
    const __hip_bfloat16* __restrict__ hidden, const float* __restrict__ Wl,
    const float* __restrict__ bl, float* __restrict__ out) {
  __shared__ float As[16][68];
  __shared__ float Bs[16][68];
  const int tid = threadIdx.x;
  const int bt = blockIdx.x * 64;
  const int bo = blockIdx.y * 64;
  const int tx = tid & 15;
  const int ty = tid >> 4;
  const int tA = tid >> 2;
  const int kq = (tid & 3) << 2;
  const unsigned short* hidu = reinterpret_cast<const unsigned short*>(hidden);

  float acc[4][4];
#pragma unroll
  for (int i = 0; i < 4; ++i)
#pragma unroll
    for (int j = 0; j < 4; ++j) acc[i][j] = 0.f;

  for (int k0 = 0; k0 < HID; k0 += 16) {
    const ushort4 av = *reinterpret_cast<const ushort4*>(
        hidu + (size_t)(bt + tA) * HID + k0 + kq);
    As[kq + 0][tA] = __uint_as_float((unsigned)av.x << 16);
    As[kq + 1][tA] = __uint_as_float((unsigned)av.y << 16);
    As[kq + 2][tA] = __uint_as_float((unsigned)av.z << 16);
    As[kq + 3][tA] = __uint_as_float((unsigned)av.w << 16);
    const float4 bv = *reinterpret_cast<const float4*>(
        Wl + (size_t)(bo + tA) * HID + k0 + kq);
    Bs[kq + 0][tA] = bv.x;
    Bs[kq + 1][tA] = bv.y;
    Bs[kq + 2][tA] = bv.z;
    Bs[kq + 3][tA] = bv.w;
    __syncthreads();
#pragma unroll
    for (int k = 0; k < 16; ++k) {
      const float4 a = *reinterpret_cast<const float4*>(&As[k][ty << 2]);
      const float4 bq = *reinterpret_cast<const float4*>(&Bs[k][tx << 2]);
      const float a4[4] = {a.x, a.y, a.z, a.w};
      const float b4[4] = {bq.x, bq.y, bq.z, bq.w};
#pragma unroll
      for (int i = 0; i < 4; ++i)
#pragma unroll
        for (int j = 0; j < 4; ++j) acc[i][j] += a4[i] * b4[j];
    }
    __syncthreads();
  }
#pragma unroll
  for (int i = 0; i < 4; ++i) {
    const int t = bt + (ty << 2) + i;
#pragma unroll
    for (int j = 0; j < 4; ++j) {
      const int o = bo + (tx << 2) + j;
      out[(size_t)t * NOUT + o] = acc[i][j] + bl[o];
    }
  }
}

extern "C" void kernel_launch(void* const* d_in, const int* in_sizes, int n_in,
                              void* d_out, int out_size, void* d_ws,
                              size_t ws_size, hipStream_t stream) {
  (void)in_sizes;
  (void)n_in;
  (void)out_size;
  (void)ws_size;
  // setup_inputs order: ts, ys, wi, wh, b, bn, Wl, bl (all f32)
  const float* ys = (const float*)d_in[1];
  const float* wi = (const float*)d_in[2];
  const float* wh = (const float*)d_in[3];
  const float* b = (const float*)d_in[4];
  const float* bn = (const float*)d_in[5];
  const float* Wl = (const float*)d_in[6];
  const float* bl = (const float*)d_in[7];
  float* out = (float*)d_out;

  u64* slots = (u64*)((char*)d_ws + WS_HBUF_OFF);
  __hip_bfloat16* hidden = (__hip_bfloat16*)((char*)d_ws + WS_HIDDEN_OFF);

  gru_init_kernel<<<8, 256, 0, stream>>>(slots);

  gru_scan_kernel<<<dim3(NBLK), dim3(NTHR), 0, stream>>>(ys, wi, wh, b, bn,
                                                         hidden, slots);

  out_gemm_kernel<<<dim3(T_STEPS / 64, NOUT / 64), 256, 0, stream>>>(
      hidden, Wl, bl, out);
}

// Round 18
// 23284.604 us; speedup vs baseline: 1.5894x; 1.5894x over previous
//
#include <hip/hip_runtime.h>
#include <hip/hip_bf16.h>

#define T_STEPS 8192
#define OBS 256
#define HID 2048
#define NOUT 256

#define NBLK 128   // scan blocks (1/CU on 128 CUs)
#define NTHR 512   // 8 waves; wave owns 2 units
#define NSLOT 512  // 16B seqlock slots (4 units each)

typedef unsigned long long u64;
typedef _Float16 half2v __attribute__((ext_vector_type(2)));
typedef __fp16 fp16x2 __attribute__((ext_vector_type(2)));

// ws layout:
//   [4096, 20480)  : h_pair, 2 buffers x 512 slots x 16B
//                    slot = [u32 tag | fp16x2 pairA | fp16x2 pairB | u32 tagback]
//   [65536, +32MB) : hidden, T x HID bf16
#define WS_HBUF_OFF 4096
#define WS_HIDDEN_OFF 65536

__global__ void gru_init_kernel(u64* h_pair) {
  h_pair[blockIdx.x * 256 + threadIdx.x] = 0ull;  // 2048 u64
}

__device__ __forceinline__ half2v bc_h2(unsigned u) {
  union { unsigned u; half2v h; } c;
  c.u = u;
  return c.h;
}
__device__ __forceinline__ unsigned pk_rn(float lo, float hi) {
  union { half2v h; unsigned u; } c;
  c.h[0] = (_Float16)lo;  // RNE
  c.h[1] = (_Float16)hi;
  return c.u;
}
__device__ __forceinline__ unsigned pk_rtz(float lo, float hi) {
  union { fp16x2 h; unsigned u; } c;
  c.h = __builtin_amdgcn_cvt_pkrtz(lo, hi);
  return c.u;
}
__device__ __forceinline__ float fdot2f(unsigned a, unsigned b, float c) {
#if __has_builtin(__builtin_amdgcn_fdot2)
  return __builtin_amdgcn_fdot2(bc_h2(a), bc_h2(b), c, false);
#else
  const half2v ha = bc_h2(a), hb = bc_h2(b);
  return c + (float)ha[0] * (float)hb[0] + (float)ha[1] * (float)hb[1];
#endif
}

// ISA-level cache-op exchange primitives (gfx950): sc0 sc1 on loads bypasses
// L1+L2 (read straight from MALL); on stores writes through to MALL (no
// dirty line left in the producer's per-XCD L2 -> no coherence probe /
// writeback chain on the consumer's miss path).
__device__ __forceinline__ void ld2_sc01(const u64* p0, const u64* p1,
                                         u64& a, u64& b) {
  asm volatile(
      "global_load_dwordx2 %0, %2, off sc0 sc1\n\t"
      "global_load_dwordx2 %1, %3, off sc0 sc1\n\t"
      "s_waitcnt vmcnt(0)"
      : "=v"(a), "=v"(b)
      : "v"(p0), "v"(p1)
      : "memory");
}
__device__ __forceinline__ u64 ld1_sc01(const u64* p) {
  u64 a;
  asm volatile(
      "global_load_dwordx2 %0, %1, off sc0 sc1\n\t"
      "s_waitcnt vmcnt(0)"
      : "=v"(a)
      : "v"(p)
      : "memory");
  return a;
}
__device__ __forceinline__ void st1_sc01(u64* p, u64 v) {
  asm volatile("global_store_dwordx2 %0, %1, off sc0 sc1"
               :
               : "v"(p), "v"(v)
               : "memory");
}

// r18 = r14 (best: 20.9ms) with the exchange moved to explicit sc0+sc1
// cache ops, and wi·x computed BEFORE the poll (critical path unchanged:
// max(other blocks' publish, own wi·x) + detect — the overlap is against
// OTHER blocks' work). Everything else byte-identical to r14:
// 128 blocks x 512 threads; block w owns units w*16..+15; wave v owns units
// w*16+2v, +2v+1 (weight rows {i,H+i,2H+i} packed fp16, asm-pinned);
// 512 16B seqlock slots; thread tid polls slot tid; ONE coalesced 64B
// publish burst per block (threads 0..7) after sync2.
__global__ __launch_bounds__(NTHR, 2) void gru_scan_kernel(
    const float* __restrict__ ys, const float* __restrict__ wi,
    const float* __restrict__ wh, const float* __restrict__ b,
    const float* __restrict__ bn, __hip_bfloat16* __restrict__ hidden,
    u64* h_pair) {
  const int w = blockIdx.x;
  const int tid = threadIdx.x;
  const int wave = tid >> 6;
  const int lane = tid & 63;

  __shared__ __align__(16) unsigned hq_lds[2][HID / 2];  // fp16x2 pairs, 2x4KB
  __shared__ unsigned pair_lds[2][8];                    // per-wave fp16x2

  // ---- one-time: stage 6 rows/wave of wh,wi as packed fp16 in VGPRs ----
  unsigned whp[6][16];
  unsigned wip[6][4];
#pragma unroll
  for (int r = 0; r < 6; ++r) {
    const int g = r >> 1, e = r & 1;
    const size_t R = (size_t)(g * HID + w * 16 + 2 * wave + e);
#pragma unroll
    for (int m = 0; m < 8; ++m) {
      const float4 q =
          *reinterpret_cast<const float4*>(wh + R * HID + m * 256 + lane * 4);
      whp[r][2 * m] = pk_rn(q.x, q.y);
      whp[r][2 * m + 1] = pk_rn(q.z, q.w);
    }
#pragma unroll
    for (int p = 0; p < 2; ++p) {
      const float4 q =
          *reinterpret_cast<const float4*>(wi + R * 512 + p * 256 + lane * 4);
      wip[r][2 * p] = pk_rn(q.x, q.y);
      wip[r][2 * p + 1] = pk_rn(q.z, q.w);
    }
  }
#pragma unroll
  for (int r = 0; r < 6; ++r) {
#pragma unroll
    for (int m = 0; m < 16; ++m) asm volatile("" : "+v"(whp[r][m]));
#pragma unroll
    for (int p = 0; p < 4; ++p) asm volatile("" : "+v"(wip[r][p]));
  }

  // Gate constants for this wave's unit (lane&1 selects which of the pair).
  const int iu = w * 16 + 2 * wave + (lane & 1);
  const float b_r = b[iu];
  const float b_z = b[HID + iu];
  const float b_n = b[2 * HID + iu];
  const float bn_v = bn[iu];

  float h_own = 0.f;  // lanes 0,1: f32 recurrence state of own unit

#pragma unroll 1
  for (int s = 0; s < T_STEPS; ++s) {
    const int buf = s & 1;
    const u64* hp = h_pair + buf * (2 * NSLOT);  // 1024 u64 per buffer
    u64* hp_next = h_pair + (buf ^ 1) * (2 * NSLOT);
    const unsigned tag = (unsigned)s;

    // ---- h-independent work FIRST (overlaps other blocks' publishes) ----
    const float4 yv =
        *reinterpret_cast<const float4*>(ys + (size_t)s * OBS + lane * 4);
    const bool k0 = (yv.x == yv.x), k1 = (yv.y == yv.y), k2 = (yv.z == yv.z),
               k3 = (yv.w == yv.w);
    unsigned xq[4];
    xq[0] = pk_rtz(k0 ? yv.x : 0.f, k1 ? yv.y : 0.f);
    xq[1] = pk_rtz(k2 ? yv.z : 0.f, k3 ? yv.w : 0.f);
    xq[2] = pk_rtz(k0 ? 1.f : 0.f, k1 ? 1.f : 0.f);
    xq[3] = pk_rtz(k2 ? 1.f : 0.f, k3 ? 1.f : 0.f);

    float pR[2], pZ[2], pIN[2];
#pragma unroll
    for (int e = 0; e < 2; ++e) {
      float ar = 0.f, az = 0.f, ain = 0.f;
#pragma unroll
      for (int p = 0; p < 4; ++p) {
        ar = fdot2f(wip[e][p], xq[p], ar);
        az = fdot2f(wip[2 + e][p], xq[p], az);
        ain = fdot2f(wip[4 + e][p], xq[p], ain);
      }
      pR[e] = ar;
      pZ[e] = az;
      pIN[e] = ain;
    }

    // ---- poll own slot straight from MALL (sc0 sc1; seqlock tags) ----
    u64 v0, v1;
    ld2_sc01(hp + 2 * tid, hp + 2 * tid + 1, v0, v1);
    while ((unsigned)(v0 >> 32) != tag || (unsigned)v1 != tag) {
      __builtin_amdgcn_s_sleep(1);
      if ((unsigned)(v0 >> 32) != tag) v0 = ld1_sc01(hp + 2 * tid);
      if ((unsigned)v1 != tag) v1 = ld1_sc01(hp + 2 * tid + 1);
    }

    // ---- stage: slot tid covers units 4*tid..+3 = pairs 2*tid, 2*tid+1 ----
    hq_lds[buf][2 * tid] = (unsigned)v0;              // pairA
    hq_lds[buf][2 * tid + 1] = (unsigned)(v1 >> 32);  // pairB
    __syncthreads();  // sync1: all 512 slots fresh + staged

    // ---- h fragments straight from LDS ----
    unsigned hq[16];
#pragma unroll
    for (int m = 0; m < 8; ++m) {
      const uint2 q =
          *reinterpret_cast<const uint2*>(&hq_lds[buf][m * 128 + lane * 2]);
      hq[2 * m] = q.x;
      hq[2 * m + 1] = q.y;
    }

    // ---- 8 dot accumulators, seeded with the wi·x partials ----
    float a[8];
#pragma unroll
    for (int e = 0; e < 2; ++e) {
      float ar = pR[e], az = pZ[e], ahn = 0.f;
      const int r0 = e, r1 = 2 + e, r2 = 4 + e;
#pragma unroll
      for (int m = 0; m < 16; ++m) {
        ar = fdot2f(whp[r0][m], hq[m], ar);
        az = fdot2f(whp[r1][m], hq[m], az);
        ahn = fdot2f(whp[r2][m], hq[m], ahn);
      }
      a[4 * e] = ar;
      a[4 * e + 1] = az;
      a[4 * e + 2] = ahn;
      a[4 * e + 3] = pIN[e];
    }

    // ---- combining butterfly: all 8 sums in 10 shuffles ----
#pragma unroll
    for (int j = 0; j < 4; ++j) {
      const bool sel = (lane & 1) != 0;
      const float keep = sel ? a[j + 4] : a[j];
      const float send = sel ? a[j] : a[j + 4];
      a[j] = keep + __shfl_xor(send, 1, 64);
    }
#pragma unroll
    for (int j = 0; j < 2; ++j) {
      const bool sel = (lane & 2) != 0;
      const float keep = sel ? a[j + 2] : a[j];
      const float send = sel ? a[j] : a[j + 2];
      a[j] = keep + __shfl_xor(send, 2, 64);
    }
    {
      const bool sel = (lane & 4) != 0;
      const float keep = sel ? a[1] : a[0];
      const float send = sel ? a[0] : a[1];
      a[0] = keep + __shfl_xor(send, 4, 64);
    }
    float redv = a[0];
    redv += __shfl_xor(redv, 8, 64);
    redv += __shfl_xor(redv, 16, 64);
    redv += __shfl_xor(redv, 32, 64);

    // Component c at lane rev3(c): r_e@lane e, z_e@4+e, hn_e@2+e, in_e@6+e.
    const int e = lane & 1;
    const float d_r = __shfl(redv, e, 64);
    const float d_z = __shfl(redv, 4 + e, 64);
    const float d_hn = __shfl(redv, 2 + e, 64);
    const float d_in = __shfl(redv, 6 + e, 64);

    // ---- gate math on all lanes (only lanes 0,1 hold valid state) ----
    const float rg = 1.f / (1.f + expf(-(d_r + b_r)));
    const float zg = 1.f / (1.f + expf(-(d_z + b_z)));
    const float ng = tanhf(d_in + b_n + rg * (d_hn + bn_v));
    const float hnew = ng + zg * (h_own - ng);
    h_own = hnew;  // garbage on lanes>=2, never consumed

    const float h1 = __shfl(hnew, 1, 64);
    if (lane == 0) {
      pair_lds[buf][wave] = pk_rtz(hnew, h1);
      // bf16 pair for the output head (off the critical path)
      const unsigned bf =
          ((unsigned)__bfloat16_as_ushort(__float2bfloat16(h1)) << 16) |
          (unsigned)__bfloat16_as_ushort(__float2bfloat16(hnew));
      *reinterpret_cast<unsigned*>(
          &hidden[(size_t)s * HID + w * 16 + 2 * wave]) = bf;
    }
    __syncthreads();  // sync2: all 8 wave-pairs in pair_lds

    // ---- aggregated publish: ONE 64B burst, write-through to MALL ----
    if (tid < 8) {
      const int q = tid >> 1;
      u64 pv;
      if ((tid & 1) == 0)  // {tag, pairA}
        pv = ((u64)(tag + 1) << 32) | (u64)pair_lds[buf][2 * q];
      else  // {pairB, tagback}
        pv = ((u64)pair_lds[buf][2 * q + 1] << 32) | (u64)(tag + 1);
      st1_sc01(hp_next + w * 8 + tid, pv);
    }
    // No end-of-step barrier: LDS double-buffered by parity; same-parity
    // reuse is separated by two block-wide sync1s.
  }
}

// out[t][o] = bl[o] + sum_k hidden[t][k] * Wl[o][k]
// 64x64 tile, 256 threads, 4x4 micro-tile, BK=16.
__global__ __launch_bounds__(256) void out_gemm_kernel(
    const __hip_bfloat16* __restrict__ hidden, const float* __restrict__ Wl,
    const float* __restrict__ bl, float* __restrict__ out) {
  __shared__ float As[16][68];
  __shared__ float Bs[16][68];
  const int tid = threadIdx.x;
  const int bt = blockIdx.x * 64;
  const int bo = blockIdx.y * 64;
  const int tx = tid & 15;
  const int ty = tid >> 4;
  const int tA = tid >> 2;
  const int kq = (tid & 3) << 2;
  const unsigned short* hidu = reinterpret_cast<const unsigned short*>(hidden);

  float acc[4][4];
#pragma unroll
  for (int i = 0; i < 4; ++i)
#pragma unroll
    for (int j = 0; j < 4; ++j) acc[i][j] = 0.f;

  for (int k0 = 0; k0 < HID; k0 += 16) {
    const ushort4 av = *reinterpret_cast<const ushort4*>(
        hidu + (size_t)(bt + tA) * HID + k0 + kq);
    As[kq + 0][tA] = __uint_as_float((unsigned)av.x << 16);
    As[kq + 1][tA] = __uint_as_float((unsigned)av.y << 16);
    As[kq + 2][tA] = __uint_as_float((unsigned)av.z << 16);
    As[kq + 3][tA] = __uint_as_float((unsigned)av.w << 16);
    const float4 bv = *reinterpret_cast<const float4*>(
        Wl + (size_t)(bo + tA) * HID + k0 + kq);
    Bs[kq + 0][tA] = bv.x;
    Bs[kq + 1][tA] = bv.y;
    Bs[kq + 2][tA] = bv.z;
    Bs[kq + 3][tA] = bv.w;
    __syncthreads();
#pragma unroll
    for (int k = 0; k < 16; ++k) {
      const float4 a = *reinterpret_cast<const float4*>(&As[k][ty << 2]);
      const float4 bq = *reinterpret_cast<const float4*>(&Bs[k][tx << 2]);
      const float a4[4] = {a.x, a.y, a.z, a.w};
      const float b4[4] = {bq.x, bq.y, bq.z, bq.w};
#pragma unroll
      for (int i = 0; i < 4; ++i)
#pragma unroll
        for (int j = 0; j < 4; ++j) acc[i][j] += a4[i] * b4[j];
    }
    __syncthreads();
  }
#pragma unroll
  for (int i = 0; i < 4; ++i) {
    const int t = bt + (ty << 2) + i;
#pragma unroll
    for (int j = 0; j < 4; ++j) {
      const int o = bo + (tx << 2) + j;
      out[(size_t)t * NOUT + o] = acc[i][j] + bl[o];
    }
  }
}

extern "C" void kernel_launch(void* const* d_in, const int* in_sizes, int n_in,
                              void* d_out, int out_size, void* d_ws,
                              size_t ws_size, hipStream_t stream) {
  (void)in_sizes;
  (void)n_in;
  (void)out_size;
  (void)ws_size;
  // setup_inputs order: ts, ys, wi, wh, b, bn, Wl, bl (all f32)
  const float* ys = (const float*)d_in[1];
  const float* wi = (const float*)d_in[2];
  const float* wh = (const float*)d_in[3];
  const float* b = (const float*)d_in[4];
  const float* bn = (const float*)d_in[5];
  const float* Wl = (const float*)d_in[6];
  const float* bl = (const float*)d_in[7];
  float* out = (float*)d_out;

  u64* h_pair = (u64*)((char*)d_ws + WS_HBUF_OFF);
  __hip_bfloat16* hidden = (__hip_bfloat16*)((char*)d_ws + WS_HIDDEN_OFF);

  gru_init_kernel<<<8, 256, 0, stream>>>(h_pair);

  gru_scan_kernel<<<dim3(NBLK), dim3(NTHR), 0, stream>>>(ys, wi, wh, b, bn,
                                                         hidden, h_pair);

  out_gemm_kernel<<<dim3(T_STEPS / 64, NOUT / 64), 256, 0, stream>>>(
      hidden, Wl, bl, out);
}

// Round 19
// 20835.274 us; speedup vs baseline: 1.7762x; 1.1176x over previous
//
#include <hip/hip_runtime.h>
#include <hip/hip_bf16.h>

#define T_STEPS 8192
#define OBS 256
#define HID 2048
#define NOUT 256

#define NBLK 128   // scan blocks (1/CU on 128 CUs)
#define NTHR 512   // 8 waves; wave owns 2 units
#define NSLOT 512  // 16B seqlock slots (4 units each)

typedef unsigned long long u64;
typedef _Float16 half2v __attribute__((ext_vector_type(2)));
typedef __fp16 fp16x2 __attribute__((ext_vector_type(2)));

// ws layout:
//   [4096, 20480)  : h_pair, 2 buffers x 512 slots x 16B
//                    slot = [u32 tag | fp16x2 pairA | fp16x2 pairB | u32 tagback]
//   [65536, +32MB) : hidden, T x HID bf16
#define WS_HBUF_OFF 4096
#define WS_HIDDEN_OFF 65536

__global__ void gru_init_kernel(u64* h_pair) {
  h_pair[blockIdx.x * 256 + threadIdx.x] = 0ull;  // 2048 u64
}

__device__ __forceinline__ half2v bc_h2(unsigned u) {
  union { unsigned u; half2v h; } c;
  c.u = u;
  return c.h;
}
__device__ __forceinline__ unsigned pk_rn(float lo, float hi) {
  union { half2v h; unsigned u; } c;
  c.h[0] = (_Float16)lo;  // RNE
  c.h[1] = (_Float16)hi;
  return c.u;
}
__device__ __forceinline__ unsigned pk_rtz(float lo, float hi) {
  union { fp16x2 h; unsigned u; } c;
  c.h = __builtin_amdgcn_cvt_pkrtz(lo, hi);
  return c.u;
}
__device__ __forceinline__ float fdot2f(unsigned a, unsigned b, float c) {
#if __has_builtin(__builtin_amdgcn_fdot2)
  return __builtin_amdgcn_fdot2(bc_h2(a), bc_h2(b), c, false);
#else
  const half2v ha = bc_h2(a), hb = bc_h2(b);
  return c + (float)ha[0] * (float)hb[0] + (float)ha[1] * (float)hb[1];
#endif
}

// r19 = r14 verbatim (best: 20.9ms, 2.57us/step) — the measured floor of the
// device-wide sequential-handoff structure after 18 rounds of lever testing.
// 128 blocks x 512 threads. Block w owns units w*16..+15; wave v owns units
// w*16+2v, +2v+1 (weight rows {i,H+i,2H+i} packed fp16, asm-pinned).
// Exchange: 512 seqlock slots of 16B; thread tid polls slot tid (2 u64
// loads/round); producer publishes all 16 units as ONE coalesced 64B burst
// (threads 0..7) after sync2 (r13/r15: scattered same-line publishes cost
// +1.1us/step via MALL line serialization). wi·x is computed in-register
// DURING the h-poll wait (x is h-independent).
__global__ __launch_bounds__(NTHR, 2) void gru_scan_kernel(
    const float* __restrict__ ys, const float* __restrict__ wi,
    const float* __restrict__ wh, const float* __restrict__ b,
    const float* __restrict__ bn, __hip_bfloat16* __restrict__ hidden,
    u64* h_pair) {
  const int w = blockIdx.x;
  const int tid = threadIdx.x;
  const int wave = tid >> 6;
  const int lane = tid & 63;

  __shared__ __align__(16) unsigned hq_lds[2][HID / 2];  // fp16x2 pairs, 2x4KB
  __shared__ unsigned pair_lds[2][8];                    // per-wave fp16x2

  // ---- one-time: stage 6 rows/wave of wh,wi as packed fp16 in VGPRs ----
  unsigned whp[6][16];
  unsigned wip[6][4];
#pragma unroll
  for (int r = 0; r < 6; ++r) {
    const int g = r >> 1, e = r & 1;
    const size_t R = (size_t)(g * HID + w * 16 + 2 * wave + e);
#pragma unroll
    for (int m = 0; m < 8; ++m) {
      const float4 q =
          *reinterpret_cast<const float4*>(wh + R * HID + m * 256 + lane * 4);
      whp[r][2 * m] = pk_rn(q.x, q.y);
      whp[r][2 * m + 1] = pk_rn(q.z, q.w);
    }
#pragma unroll
    for (int p = 0; p < 2; ++p) {
      const float4 q =
          *reinterpret_cast<const float4*>(wi + R * 512 + p * 256 + lane * 4);
      wip[r][2 * p] = pk_rn(q.x, q.y);
      wip[r][2 * p + 1] = pk_rn(q.z, q.w);
    }
  }
#pragma unroll
  for (int r = 0; r < 6; ++r) {
#pragma unroll
    for (int m = 0; m < 16; ++m) asm volatile("" : "+v"(whp[r][m]));
#pragma unroll
    for (int p = 0; p < 4; ++p) asm volatile("" : "+v"(wip[r][p]));
  }

  // Gate constants for this wave's unit (lane&1 selects which of the pair).
  const int iu = w * 16 + 2 * wave + (lane & 1);
  const float b_r = b[iu];
  const float b_z = b[HID + iu];
  const float b_n = b[2 * HID + iu];
  const float bn_v = bn[iu];

  float h_own = 0.f;  // lanes 0,1: f32 recurrence state of own unit

#pragma unroll 1
  for (int s = 0; s < T_STEPS; ++s) {
    const int buf = s & 1;
    const u64* hp = h_pair + buf * (2 * NSLOT);  // 1024 u64 per buffer
    u64* hp_next = h_pair + (buf ^ 1) * (2 * NSLOT);
    const unsigned tag = (unsigned)s;

    // ---- issue poll loads FIRST (longest latency) ----
    u64 v0 = __hip_atomic_load(hp + 2 * tid, __ATOMIC_RELAXED,
                               __HIP_MEMORY_SCOPE_AGENT);
    u64 v1 = __hip_atomic_load(hp + 2 * tid + 1, __ATOMIC_RELAXED,
                               __HIP_MEMORY_SCOPE_AGENT);

    // ---- h-independent work, overlapped with the poll wait ----
    // lane's own x fragment: obs[4*lane .. 4*lane+3] (row L2-hot after wave 0)
    const float4 yv =
        *reinterpret_cast<const float4*>(ys + (size_t)s * OBS + lane * 4);
    const bool k0 = (yv.x == yv.x), k1 = (yv.y == yv.y), k2 = (yv.z == yv.z),
               k3 = (yv.w == yv.w);
    unsigned xq[4];
    xq[0] = pk_rtz(k0 ? yv.x : 0.f, k1 ? yv.y : 0.f);
    xq[1] = pk_rtz(k2 ? yv.z : 0.f, k3 ? yv.w : 0.f);
    xq[2] = pk_rtz(k0 ? 1.f : 0.f, k1 ? 1.f : 0.f);
    xq[3] = pk_rtz(k2 ? 1.f : 0.f, k3 ? 1.f : 0.f);

    // 6 wi·x partial dots (seed values for the post-sync accumulators)
    float pR[2], pZ[2], pIN[2];
#pragma unroll
    for (int e = 0; e < 2; ++e) {
      float ar = 0.f, az = 0.f, ain = 0.f;
#pragma unroll
      for (int p = 0; p < 4; ++p) {
        ar = fdot2f(wip[e][p], xq[p], ar);
        az = fdot2f(wip[2 + e][p], xq[p], az);
        ain = fdot2f(wip[4 + e][p], xq[p], ain);
      }
      pR[e] = ar;
      pZ[e] = az;
      pIN[e] = ain;
    }

    // ---- finish poll (seqlock tags at both ends of the 16B slot) ----
    while ((unsigned)(v0 >> 32) != tag || (unsigned)v1 != tag) {
      __builtin_amdgcn_s_sleep(1);
      v0 = __hip_atomic_load(hp + 2 * tid, __ATOMIC_RELAXED,
                             __HIP_MEMORY_SCOPE_AGENT);
      v1 = __hip_atomic_load(hp + 2 * tid + 1, __ATOMIC_RELAXED,
                             __HIP_MEMORY_SCOPE_AGENT);
    }

    // ---- stage: slot tid covers units 4*tid..+3 = pairs 2*tid, 2*tid+1 ----
    hq_lds[buf][2 * tid] = (unsigned)v0;              // pairA
    hq_lds[buf][2 * tid + 1] = (unsigned)(v1 >> 32);  // pairB
    __syncthreads();  // sync1: all 512 slots fresh + staged

    // ---- h fragments straight from LDS ----
    unsigned hq[16];
#pragma unroll
    for (int m = 0; m < 8; ++m) {
      const uint2 q =
          *reinterpret_cast<const uint2*>(&hq_lds[buf][m * 128 + lane * 2]);
      hq[2 * m] = q.x;
      hq[2 * m + 1] = q.y;
    }

    // ---- 8 dot accumulators, seeded with the wi·x partials ----
    float a[8];
#pragma unroll
    for (int e = 0; e < 2; ++e) {
      float ar = pR[e], az = pZ[e], ahn = 0.f;
      const int r0 = e, r1 = 2 + e, r2 = 4 + e;
#pragma unroll
      for (int m = 0; m < 16; ++m) {
        ar = fdot2f(whp[r0][m], hq[m], ar);
        az = fdot2f(whp[r1][m], hq[m], az);
        ahn = fdot2f(whp[r2][m], hq[m], ahn);
      }
      a[4 * e] = ar;
      a[4 * e + 1] = az;
      a[4 * e + 2] = ahn;
      a[4 * e + 3] = pIN[e];
    }

    // ---- combining butterfly: all 8 sums in 10 shuffles ----
#pragma unroll
    for (int j = 0; j < 4; ++j) {
      const bool sel = (lane & 1) != 0;
      const float keep = sel ? a[j + 4] : a[j];
      const float send = sel ? a[j] : a[j + 4];
      a[j] = keep + __shfl_xor(send, 1, 64);
    }
#pragma unroll
    for (int j = 0; j < 2; ++j) {
      const bool sel = (lane & 2) != 0;
      const float keep = sel ? a[j + 2] : a[j];
      const float send = sel ? a[j] : a[j + 2];
      a[j] = keep + __shfl_xor(send, 2, 64);
    }
    {
      const bool sel = (lane & 4) != 0;
      const float keep = sel ? a[1] : a[0];
      const float send = sel ? a[0] : a[1];
      a[0] = keep + __shfl_xor(send, 4, 64);
    }
    float redv = a[0];
    redv += __shfl_xor(redv, 8, 64);
    redv += __shfl_xor(redv, 16, 64);
    redv += __shfl_xor(redv, 32, 64);

    // Component c at lane rev3(c): r_e@lane e, z_e@4+e, hn_e@2+e, in_e@6+e.
    const int e = lane & 1;
    const float d_r = __shfl(redv, e, 64);
    const float d_z = __shfl(redv, 4 + e, 64);
    const float d_hn = __shfl(redv, 2 + e, 64);
    const float d_in = __shfl(redv, 6 + e, 64);

    // ---- gate math on all lanes (only lanes 0,1 hold valid state) ----
    const float rg = 1.f / (1.f + expf(-(d_r + b_r)));
    const float zg = 1.f / (1.f + expf(-(d_z + b_z)));
    const float ng = tanhf(d_in + b_n + rg * (d_hn + bn_v));
    const float hnew = ng + zg * (h_own - ng);
    h_own = hnew;  // garbage on lanes>=2, never consumed

    const float h1 = __shfl(hnew, 1, 64);
    if (lane == 0) {
      pair_lds[buf][wave] = pk_rtz(hnew, h1);
      // bf16 pair for the output head (off the critical path)
      const unsigned bf =
          ((unsigned)__bfloat16_as_ushort(__float2bfloat16(h1)) << 16) |
          (unsigned)__bfloat16_as_ushort(__float2bfloat16(hnew));
      *reinterpret_cast<unsigned*>(
          &hidden[(size_t)s * HID + w * 16 + 2 * wave]) = bf;
    }
    __syncthreads();  // sync2: all 8 wave-pairs in pair_lds

    // ---- aggregated publish: ONE 64B burst (8 lanes x u64, seqlock) ----
    if (tid < 8) {
      const int q = tid >> 1;
      u64 pv;
      if ((tid & 1) == 0)  // {tag, pairA}
        pv = ((u64)(tag + 1) << 32) | (u64)pair_lds[buf][2 * q];
      else  // {pairB, tagback}
        pv = ((u64)pair_lds[buf][2 * q + 1] << 32) | (u64)(tag + 1);
      __hip_atomic_store(hp_next + w * 8 + tid, pv, __ATOMIC_RELAXED,
                         __HIP_MEMORY_SCOPE_AGENT);
    }
    // No end-of-step barrier: LDS double-buffered by parity; same-parity
    // reuse is separated by two block-wide sync1s.
  }
}

// out[t][o] = bl[o] + sum_k hidden[t][k] * Wl[o][k]
// 64x64 tile, 256 threads, 4x4 micro-tile, BK=16.
__global__ __launch_bounds__(256) void out_gemm_kernel(
    const __hip_bfloat16* __restrict__ hidden, const float* __restrict__ Wl,
    const float* __restrict__ bl, float* __restrict__ out) {
  __shared__ float As[16][68];
  __shared__ float Bs[16][68];
  const int tid = threadIdx.x;
  const int bt = blockIdx.x * 64;
  const int bo = blockIdx.y * 64;
  const int tx = tid & 15;
  const int ty = tid >> 4;
  const int tA = tid >> 2;
  const int kq = (tid & 3) << 2;
  const unsigned short* hidu = reinterpret_cast<const unsigned short*>(hidden);

  float acc[4][4];
#pragma unroll
  for (int i = 0; i < 4; ++i)
#pragma unroll
    for (int j = 0; j < 4; ++j) acc[i][j] = 0.f;

  for (int k0 = 0; k0 < HID; k0 += 16) {
    const ushort4 av = *reinterpret_cast<const ushort4*>(
        hidu + (size_t)(bt + tA) * HID + k0 + kq);
    As[kq + 0][tA] = __uint_as_float((unsigned)av.x << 16);
    As[kq + 1][tA] = __uint_as_float((unsigned)av.y << 16);
    As[kq + 2][tA] = __uint_as_float((unsigned)av.z << 16);
    As[kq + 3][tA] = __uint_as_float((unsigned)av.w << 16);
    const float4 bv = *reinterpret_cast<const float4*>(
        Wl + (size_t)(bo + tA) * HID + k0 + kq);
    Bs[kq + 0][tA] = bv.x;
    Bs[kq + 1][tA] = bv.y;
    Bs[kq + 2][tA] = bv.z;
    Bs[kq + 3][tA] = bv.w;
    __syncthreads();
#pragma unroll
    for (int k = 0; k < 16; ++k) {
      const float4 a = *reinterpret_cast<const float4*>(&As[k][ty << 2]);
      const float4 bq = *reinterpret_cast<const float4*>(&Bs[k][tx << 2]);
      const float a4[4] = {a.x, a.y, a.z, a.w};
      const float b4[4] = {bq.x, bq.y, bq.z, bq.w};
#pragma unroll
      for (int i = 0; i < 4; ++i)
#pragma unroll
        for (int j = 0; j < 4; ++j) acc[i][j] += a4[i] * b4[j];
    }
    __syncthreads();
  }
#pragma unroll
  for (int i = 0; i < 4; ++i) {
    const int t = bt + (ty << 2) + i;
#pragma unroll
    for (int j = 0; j < 4; ++j) {
      const int o = bo + (tx << 2) + j;
      out[(size_t)t * NOUT + o] = acc[i][j] + bl[o];
    }
  }
}

extern "C" void kernel_launch(void* const* d_in, const int* in_sizes, int n_in,
                              void* d_out, int out_size, void* d_ws,
                              size_t ws_size, hipStream_t stream) {
  (void)in_sizes;
  (void)n_in;
  (void)out_size;
  (void)ws_size;
  // setup_inputs order: ts, ys, wi, wh, b, bn, Wl, bl (all f32)
  const float* ys = (const float*)d_in[1];
  const float* wi = (const float*)d_in[2];
  const float* wh = (const float*)d_in[3];
  const float* b = (const float*)d_in[4];
  const float* bn = (const float*)d_in[5];
  const float* Wl = (const float*)d_in[6];
  const float* bl = (const float*)d_in[7];
  float* out = (float*)d_out;

  u64* h_pair = (u64*)((char*)d_ws + WS_HBUF_OFF);
  __hip_bfloat16* hidden = (__hip_bfloat16*)((char*)d_ws + WS_HIDDEN_OFF);

  gru_init_kernel<<<8, 256, 0, stream>>>(h_pair);

  gru_scan_kernel<<<dim3(NBLK), dim3(NTHR), 0, stream>>>(ys, wi, wh, b, bn,
                                                         hidden, h_pair);

  out_gemm_kernel<<<dim3(T_STEPS / 64, NOUT / 64), 256, 0, stream>>>(
      hidden, Wl, bl, out);
}